// Round 2
// baseline (202.701 us; speedup 1.0000x reference)
//
#include <hip/hip_runtime.h>

// DCT compression: (32,3,512,512) fp32 -> (32,192,64,64) fp32
// Per 8x8 block: coef[a,u] = sum_{y,x} blk[y,x]*C8[a,y]*C8[u,x]
//   C8[u,y] = cos((u+0.5)*PI*y/8), PI = 3.1415 (module's approximation!)
// norm[a,u] = (a==0||u==0) ? sqrt(2)/8 : 0.25
// out[b, c*64 + z[a*8+u], hb, wb] = coef[a,u]*norm[a,u] / Qtab[c][z[a*8+u]]
//
// R2: no LDS; basis/scales/offsets in d_ws (uniform -> scalar loads);
//     per-a interleaved stores; nontemporal stores; launch_bounds(256,6).

#define PI_F 3.1415f

// Q=50 -> s=100 -> Q_luma = floor((100*T+50)/100) = T exactly (integers)
__device__ __constant__ int QTAB[2][64] = {
    {16,11,10,16,24,40,51,61,
     12,12,14,19,26,58,60,55,
     14,13,16,24,40,57,69,56,
     14,17,22,29,51,87,80,62,
     18,22,37,56,68,109,103,77,
     24,35,55,64,81,104,113,92,
     49,64,78,87,103,121,120,101,
     72,92,95,98,112,100,103,99},
    {17,18,24,47,99,99,99,99,
     18,21,26,66,99,99,99,99,
     24,26,56,99,99,99,99,99,
     47,66,99,99,99,99,99,99,
     99,99,99,99,99,99,99,99,
     99,99,99,99,99,99,99,99,
     99,99,99,99,99,99,99,99,
     99,99,99,99,99,99,99,99}
};

// ws float layout: [0,64) C8[u*8+y] ; [64,128) scale_luma[a*8+u] ;
//                  [128,192) scale_chroma[a*8+u] ; [192,256) zoff[a*8+u] (int, elements)
__global__ void dct_init_kernel(float* __restrict__ ws) {
    const int tid = threadIdx.x;  // 64 threads
    const int u = tid >> 3, y = tid & 7;
    ws[tid] = cosf(((float)u + 0.5f) * PI_F * ((float)y * 0.125f));
    if (tid == 0) {
        // faithful port of reference _zigzag(8); p is pre-transpose pattern
        int p[64];
        for (int yy = 0; yy < 8; ++yy)
            for (int xx = (yy & 1); xx < 8 - yy; xx += 2) {
                int v = xx + yy + 1;
                p[yy * 8 + xx] = v * (v + 1) / 2 - xx - 1;
            }
        for (int yy = 0; yy < 8; ++yy)
            for (int xx = ((yy + 1) & 1); xx < 8 - yy; xx += 2) {
                int v = xx + yy + 1;
                p[yy * 8 + xx] = v * (v + 1) / 2 - yy - 1;
            }
        for (int yy = 7; yy >= 0; --yy)
            for (int xx = 7; xx >= 8 - yy; --xx)
                p[yy * 8 + xx] = 63 - p[(7 - yy) * 8 + (7 - xx)];
        int* zoff = (int*)(ws + 192);
        for (int i = 0; i < 64; ++i) {
            int a = i >> 3, uu = i & 7;
            int zi = p[uu * 8 + a];  // z = p.T
            zoff[i] = zi << 12;      // * 64*64 element offset
            float nrm = (a == 0 || uu == 0) ? 0.17677669529663687f : 0.25f;
            ws[64 + i]  = nrm / (float)QTAB[0][zi];
            ws[128 + i] = nrm / (float)QTAB[1][zi];
        }
    }
}

// Grid: 1536 workgroups of 256 threads.
//   blockIdx.x = bc*16 + hbg;  bc = b*3+c in [0,96);  hbg in [0,16)
//   wave (tid>>6) picks hb = hbg*4 + wave;  lane (tid&63) = wb.
__global__ __launch_bounds__(256, 6)
void DCTCompression_25786983645730_kernel(const float* __restrict__ x,
                                          float* __restrict__ out,
                                          const float* __restrict__ ws) {
    const int tid = threadIdx.x;
    const int idx = blockIdx.x;
    const int hbg = idx & 15;
    const int bc  = idx >> 4;     // b*3 + c
    const int c   = bc % 3;

    const float* __restrict__ cb   = ws;                         // C8
    const float* __restrict__ sc   = (c == 0) ? ws + 64 : ws + 128;
    const int*   __restrict__ zoff = (const int*)(ws + 192);

    const int wave = tid >> 6;
    const int wb   = tid & 63;
    const int hb   = hbg * 4 + wave;

    const float* xb = x + ((size_t)bc * 512 + (size_t)hb * 8) * 512 + wb * 8;
    float* ob = out + (size_t)bc * 262144 + hb * 64 + wb;

    // ---- load 8x8 block: 16 independent float4 loads (coalesced) ----
    float4 r[8][2];
#pragma unroll
    for (int y = 0; y < 8; ++y) {
        r[y][0] = *reinterpret_cast<const float4*>(xb + y * 512);
        r[y][1] = *reinterpret_cast<const float4*>(xb + y * 512 + 4);
    }

    // ---- per output row a: tmp[x] = sum_y C8[a,y]*blk[y,x]; then 8 coefs + stores ----
#pragma unroll
    for (int a = 0; a < 8; ++a) {
        float tmp[8] = {0, 0, 0, 0, 0, 0, 0, 0};
#pragma unroll
        for (int y = 0; y < 8; ++y) {
            float cv = cb[a * 8 + y];  // uniform -> s_load
            tmp[0] = fmaf(cv, r[y][0].x, tmp[0]);
            tmp[1] = fmaf(cv, r[y][0].y, tmp[1]);
            tmp[2] = fmaf(cv, r[y][0].z, tmp[2]);
            tmp[3] = fmaf(cv, r[y][0].w, tmp[3]);
            tmp[4] = fmaf(cv, r[y][1].x, tmp[4]);
            tmp[5] = fmaf(cv, r[y][1].y, tmp[5]);
            tmp[6] = fmaf(cv, r[y][1].z, tmp[6]);
            tmp[7] = fmaf(cv, r[y][1].w, tmp[7]);
        }
#pragma unroll
        for (int u = 0; u < 8; ++u) {
            float acc = tmp[0] * cb[u * 8 + 0];
#pragma unroll
            for (int xx = 1; xx < 8; ++xx)
                acc = fmaf(tmp[xx], cb[u * 8 + xx], acc);
            const int j = a * 8 + u;
            // uniform zoff/scale -> scalar; store coalesced across wave (wb contig)
            __builtin_nontemporal_store(acc * sc[j], ob + zoff[j]);
        }
    }
}

extern "C" void kernel_launch(void* const* d_in, const int* in_sizes, int n_in,
                              void* d_out, int out_size, void* d_ws, size_t ws_size,
                              hipStream_t stream) {
    const float* x = (const float*)d_in[0];
    float* out = (float*)d_out;
    float* ws = (float*)d_ws;
    dct_init_kernel<<<dim3(1), dim3(64), 0, stream>>>(ws);
    // B*C*(H/8/4) = 32*3*16 = 1536 workgroups, 256 threads each
    DCTCompression_25786983645730_kernel<<<dim3(1536), dim3(256), 0, stream>>>(x, out, ws);
}